// Round 9
// baseline (681.306 us; speedup 1.0000x reference)
//
#include <hip/hip_runtime.h>
#include <cstddef>

// SkipGRU on MI355X (gfx950) — round 14.
// Ledger: 2 blk/CU (503/509) >> 1 blk/CU (588/602) regardless of LDS bytes;
// chunk count nearly free (r10); barrier rate neutral (r9) -> gru_step is
// LATENCY-bound (~70% idle, MFMA busy ~6us of 29). Fix: add INDEPENDENT
// co-resident work. Each launch t = 1024 blocks:
//   role 0 (512 blocks): GRU step t  — h@U 16 chunks + gx[t] fragments in
//                        epilogue (r10 gru_step, proven correct).
//   role 1 (512 blocks): x@W for t+1 — 16 chunks, writes gx[t+1] fragments
//                        (r10 xw_gemm, proven correct). Skipped at t=15.
// Role bit = (idx>>3)&1 -> XCDs get alternating 8-block batches of each
// role; CUs host one GRU + one XW block; XW's streaming GEMM fills GRU's
// dependency stalls. t=0 GRU blocks compute their own x@W (champion first
// branch). gx = f32 fragment layout, ping-pong 2 x 24MB in workspace —
// identical math to r10 (absmax 0.03125 there).
//
// Layouts:
//  xb[t][nb(64)][kt(16)][g(4)][row(64)][8] bf16 granules (16B).
//  Bt[cc(24)][kt(32)][g(4)][col(64)][8]    (cc = 64 gemm-cols).
//  h ping-pong: granule layout per nb.  gx[gi(512)][j(12)][tid(256)] floatx4,
//  gi = nb*8+hb, j = gate*4 + mi*2 + ci.

typedef unsigned short u16;
typedef __attribute__((ext_vector_type(8))) short short8;
typedef __attribute__((ext_vector_type(8))) u16 u16x8;
typedef __attribute__((ext_vector_type(4))) float floatx4;

#define MFMA16(a, b, c) __builtin_amdgcn_mfma_f32_16x16x32_bf16((a), (b), (c), 0, 0, 0)

__device__ __forceinline__ u16 f32_to_bf16(float f) {
  union { float f; unsigned int u; } c; c.f = f;
  unsigned int u = c.u + 0x7FFFu + ((c.u >> 16) & 1u);  // RNE
  return (u16)(u >> 16);
}
__device__ __forceinline__ float bf16_to_f32(u16 v) {
  union { unsigned int u; float f; } c; c.u = ((unsigned int)v) << 16;
  return c.f;
}
__device__ __forceinline__ float sigmoidf_(float x) {
  return 1.0f / (1.0f + __expf(-x));
}
__device__ __forceinline__ void gload_lds16(const void* g, void* l) {
  __builtin_amdgcn_global_load_lds(
      (const __attribute__((address_space(1))) unsigned int*)g,
      (__attribute__((address_space(3))) unsigned int*)l, 16, 0, 0);
}

// ---------------------------------------------------------------------------
// pack_x: coalesced. Block = one (t, nb): 64 rows x 512 c. (unchanged)
// ---------------------------------------------------------------------------
__global__ __launch_bounds__(256)
void pack_x(const float* __restrict__ x, u16* __restrict__ xb) {
  __shared__ u16 sm[64 * 512];              // 64KB
  const int t = blockIdx.x >> 6;
  const int nb = blockIdx.x & 63;
  const int tid = threadIdx.x;
#pragma unroll
  for (int it = 0; it < 16; ++it) {
    int idx = it * 256 + tid;
    int row = idx >> 6, ch = idx & 63;      // row 0..63, ch = 8-float chunk
    int xrow = (nb * 2 + (row >> 5)) * 512 + t * 32 + (row & 31);
    const float* src = x + (size_t)xrow * 512 + ch * 8;
    floatx4 va = *(const floatx4*)src;
    floatx4 vb = *(const floatx4*)(src + 4);
    u16x8 pk;
    pk[0] = f32_to_bf16(va[0]); pk[1] = f32_to_bf16(va[1]);
    pk[2] = f32_to_bf16(va[2]); pk[3] = f32_to_bf16(va[3]);
    pk[4] = f32_to_bf16(vb[0]); pk[5] = f32_to_bf16(vb[1]);
    pk[6] = f32_to_bf16(vb[2]); pk[7] = f32_to_bf16(vb[3]);
    *(u16x8*)&sm[row * 512 + (ch ^ (row & 7)) * 8] = pk;
  }
  __syncthreads();
  u16* dst = xb + (size_t)blockIdx.x * 32768;   // blockIdx = t*64+nb = layout order
#pragma unroll
  for (int it = 0; it < 16; ++it) {
    int idx = it * 256 + tid;
    int row = idx & 63, g = (idx >> 6) & 3, kt = idx >> 8;
    int ch = kt * 4 + g;
    u16x8 vv = *(const u16x8*)&sm[row * 512 + (ch ^ (row & 7)) * 8];
    *(u16x8*)(dst + (size_t)idx * 8) = vv;
  }
}

// ---------------------------------------------------------------------------
// pack_Bt: [W;U] -> Bt bf16 [cc(24)][kt(32)][g(4)][col(64)][8] (unchanged)
// ---------------------------------------------------------------------------
__global__ void pack_Bt(const float* __restrict__ W, const float* __restrict__ U,
                        u16* __restrict__ Bt) {
  size_t gid = (size_t)blockIdx.x * 256 + threadIdx.x;   // < 196608
  int col = (int)(gid & 63);
  int g   = (int)((gid >> 6) & 3);
  int kt  = (int)((gid >> 8) & 31);
  int cc  = (int)(gid >> 13);
  int c = cc * 64 + col;
  int k0 = kt * 32 + g * 8;
  u16x8 pk;
#pragma unroll
  for (int j = 0; j < 8; ++j) {
    int k = k0 + j;
    float v = (k < 512) ? W[(size_t)k * 1536 + c] : U[(size_t)(k - 512) * 1536 + c];
    pk[j] = f32_to_bf16(v);
  }
  *(u16x8*)(Bt + gid * 8) = pk;
}

// ---------------------------------------------------------------------------
// step_fused: grid 1024 x 256. Block decode: s=idx&7 (XCD slot),
// role=(idx>>3)&1, p=idx>>4 (0..63): hb=p&7, nb=((p>>3)<<3)|s.
// role 0: GRU step t (h@U 16 chunks, or x@W at t=0) + epilogue.
// role 1: x@W for t+1 -> gx_out fragments (exit at t=15).
// Both: 64n x 192c tile, 4 waves, 4x16KB LDS ring, counted-vmcnt pipeline.
// ---------------------------------------------------------------------------
__global__ __launch_bounds__(256)
void step_fused(const u16* __restrict__ xb, const u16* __restrict__ Bt,
                const float* __restrict__ bias,
                const u16* __restrict__ h_in, u16* __restrict__ h_out,
                const float* __restrict__ gx_in, float* __restrict__ gx_out,
                float* __restrict__ out, int t, int first, int last) {
  __shared__ alignas(16) char sm[65536];    // 4 x 16KB ring -> 2 blocks/CU
  const int tid = threadIdx.x;
  const int idx = blockIdx.x;
  const int s = idx & 7;
  const int role = (idx >> 3) & 1;
  const int p = idx >> 4;                   // 0..63
  const int hb = p & 7;
  const int nb = ((p >> 3) << 3) | s;       // 0..63; same-nb blocks same XCD slot
  const int gi = nb * 8 + hb;               // gx tile index, 0..511
  const int w = __builtin_amdgcn_readfirstlane(tid >> 6);  // SGPR wave id
  const int lane = tid & 63;
  const int wy = w >> 1, wx = w & 1;
  const int q = lane >> 4, lc = lane & 15;
  const int cs0 = hb, cs1 = 8 + hb, cs2 = 16 + hb;
  const int wo = w * 1024;

  if (role) {
    // ---- XW: x@W for step t+1, tile (nb, hb) -> gx_out fragments.
    if (last) return;
    const u16* aB = xb + (size_t)((t + 1) * 64 + nb) * 32768;
    floatx4 aZ[2][2] = {{{0.f,0.f,0.f,0.f},{0.f,0.f,0.f,0.f}},{{0.f,0.f,0.f,0.f},{0.f,0.f,0.f,0.f}}};
    floatx4 aR[2][2] = {{{0.f,0.f,0.f,0.f},{0.f,0.f,0.f,0.f}},{{0.f,0.f,0.f,0.f},{0.f,0.f,0.f,0.f}}};
    floatx4 aX[2][2] = {{{0.f,0.f,0.f,0.f},{0.f,0.f,0.f,0.f}},{{0.f,0.f,0.f,0.f},{0.f,0.f,0.f,0.f}}};
    auto stageW = [&](int kt, int bsel) {
      char* lds = sm + bsel * 16384;
      gload_lds16((const char*)(aB + (size_t)kt * 2048) + wo + lane * 16, lds + wo);
      gload_lds16((const char*)(Bt + (size_t)(cs0 * 32 + kt) * 2048) + wo + lane * 16,
                  lds + 4096 + wo);
      gload_lds16((const char*)(Bt + (size_t)(cs1 * 32 + kt) * 2048) + wo + lane * 16,
                  lds + 8192 + wo);
      gload_lds16((const char*)(Bt + (size_t)(cs2 * 32 + kt) * 2048) + wo + lane * 16,
                  lds + 12288 + wo);
    };
    auto computeW = [&](int slot) {
      const char* lds = sm + slot * 16384;
      short8 a0 = *(const short8*)(lds + (q * 64 + wy * 32 + lc) * 16);
      short8 a1 = *(const short8*)(lds + (q * 64 + wy * 32 + 16 + lc) * 16);
#pragma unroll
      for (int ci = 0; ci < 2; ++ci) {
        int co = (q * 64 + wx * 32 + ci * 16 + lc) * 16;
        short8 bz = *(const short8*)(lds + 4096 + co);
        short8 br = *(const short8*)(lds + 8192 + co);
        short8 bh = *(const short8*)(lds + 12288 + co);
        aZ[0][ci] = MFMA16(a0, bz, aZ[0][ci]);
        aZ[1][ci] = MFMA16(a1, bz, aZ[1][ci]);
        aR[0][ci] = MFMA16(a0, br, aR[0][ci]);
        aR[1][ci] = MFMA16(a1, br, aR[1][ci]);
        aX[0][ci] = MFMA16(a0, bh, aX[0][ci]);
        aX[1][ci] = MFMA16(a1, bh, aX[1][ci]);
      }
    };
    stageW(0, 0); stageW(1, 1); stageW(2, 2);
    for (int kt = 0; kt < 14; ++kt) {
      asm volatile("s_waitcnt vmcnt(8)" ::: "memory");
      __builtin_amdgcn_s_barrier();
      if (kt < 13) stageW(kt + 3, (kt + 3) & 3);
      __builtin_amdgcn_s_setprio(1);
      computeW(kt & 3);
      __builtin_amdgcn_s_setprio(0);
    }
    asm volatile("s_waitcnt vmcnt(4)" ::: "memory");
    __builtin_amdgcn_s_barrier();
    __builtin_amdgcn_s_setprio(1);
    computeW(2);                            // kt=14
    __builtin_amdgcn_s_setprio(0);
    asm volatile("s_waitcnt vmcnt(0)" ::: "memory");
    __builtin_amdgcn_s_barrier();
    __builtin_amdgcn_s_setprio(1);
    computeW(3);                            // kt=15
    __builtin_amdgcn_s_setprio(0);
    float* base = gx_out + (size_t)gi * 12288;  // 12 planes x 256 tid x 4 f32
#pragma unroll
    for (int mi = 0; mi < 2; ++mi)
#pragma unroll
      for (int ci = 0; ci < 2; ++ci) {
        int j = mi * 2 + ci;
        *(floatx4*)(base + (size_t)(0 + j) * 1024 + tid * 4) = aZ[mi][ci];
        *(floatx4*)(base + (size_t)(4 + j) * 1024 + tid * 4) = aR[mi][ci];
        *(floatx4*)(base + (size_t)(8 + j) * 1024 + tid * 4) = aX[mi][ci];
      }
    return;
  }

  // ---- GRU step t: h@U 16 chunks (or x@W at t=0), then epilogue with gx_in.
  const u16* xbB = xb + (size_t)(t * 64 + nb) * 32768;
  const u16* htB = h_in + (size_t)nb * 32768;
  floatx4 acZ[2][2] = {{{0.f,0.f,0.f,0.f},{0.f,0.f,0.f,0.f}},{{0.f,0.f,0.f,0.f},{0.f,0.f,0.f,0.f}}};
  floatx4 acR[2][2] = {{{0.f,0.f,0.f,0.f},{0.f,0.f,0.f,0.f}},{{0.f,0.f,0.f,0.f},{0.f,0.f,0.f,0.f}}};
  floatx4 acT[2][2] = {{{0.f,0.f,0.f,0.f},{0.f,0.f,0.f,0.f}},{{0.f,0.f,0.f,0.f},{0.f,0.f,0.f,0.f}}};

  auto stage = [&](int kt, int bsel) {
    char* lds = sm + bsel * 16384;
    const char* aS = first ? (const char*)(xbB + (size_t)kt * 2048)
                           : (const char*)(htB + (size_t)kt * 2048);
    const int kc = first ? kt : (16 + kt);  // W rows at t=0, U rows otherwise
    gload_lds16(aS + wo + lane * 16, lds + wo);
    gload_lds16((const char*)(Bt + (size_t)(cs0 * 32 + kc) * 2048) + wo + lane * 16,
                lds + 4096 + wo);
    gload_lds16((const char*)(Bt + (size_t)(cs1 * 32 + kc) * 2048) + wo + lane * 16,
                lds + 8192 + wo);
    gload_lds16((const char*)(Bt + (size_t)(cs2 * 32 + kc) * 2048) + wo + lane * 16,
                lds + 12288 + wo);
  };
  auto compute = [&](int slot) {
    const char* lds = sm + slot * 16384;
    short8 a0 = *(const short8*)(lds + (q * 64 + wy * 32 + lc) * 16);
    short8 a1 = *(const short8*)(lds + (q * 64 + wy * 32 + 16 + lc) * 16);
#pragma unroll
    for (int ci = 0; ci < 2; ++ci) {
      int co = (q * 64 + wx * 32 + ci * 16 + lc) * 16;
      short8 bz = *(const short8*)(lds + 4096 + co);
      short8 br = *(const short8*)(lds + 8192 + co);
      short8 bh = *(const short8*)(lds + 12288 + co);
      acZ[0][ci] = MFMA16(a0, bz, acZ[0][ci]);
      acZ[1][ci] = MFMA16(a1, bz, acZ[1][ci]);
      acR[0][ci] = MFMA16(a0, br, acR[0][ci]);
      acR[1][ci] = MFMA16(a1, br, acR[1][ci]);
      acT[0][ci] = MFMA16(a0, bh, acT[0][ci]);
      acT[1][ci] = MFMA16(a1, bh, acT[1][ci]);
    }
  };

  stage(0, 0); stage(1, 1); stage(2, 2);
  for (int kt = 0; kt < 14; ++kt) {
    asm volatile("s_waitcnt vmcnt(8)" ::: "memory");
    __builtin_amdgcn_s_barrier();
    if (kt < 13) stage(kt + 3, (kt + 3) & 3);
    __builtin_amdgcn_s_setprio(1);
    compute(kt & 3);
    __builtin_amdgcn_s_setprio(0);
  }
  asm volatile("s_waitcnt vmcnt(4)" ::: "memory");
  __builtin_amdgcn_s_barrier();
  __builtin_amdgcn_s_setprio(1);
  compute(2);                               // kt=14
  __builtin_amdgcn_s_setprio(0);
  asm volatile("s_waitcnt vmcnt(0)" ::: "memory");
  __builtin_amdgcn_s_barrier();
  __builtin_amdgcn_s_setprio(1);
  compute(3);                               // kt=15
  __builtin_amdgcn_s_setprio(0);

  // ---- Epilogue. C/D layout: col = lane&15, row = q*4 + reg.
  __syncthreads();                          // all compute done before Ct reuse
  floatx4 xpZ[2][2], xpR[2][2], xpX[2][2];
  if (!first) {
    const float* xbase = gx_in + (size_t)gi * 12288;
#pragma unroll
    for (int mi = 0; mi < 2; ++mi)
#pragma unroll
      for (int ci = 0; ci < 2; ++ci) {
        int j = mi * 2 + ci;
        xpZ[mi][ci] = *(const floatx4*)(xbase + (size_t)(0 + j) * 1024 + tid * 4);
        xpR[mi][ci] = *(const floatx4*)(xbase + (size_t)(4 + j) * 1024 + tid * 4);
        xpX[mi][ci] = *(const floatx4*)(xbase + (size_t)(8 + j) * 1024 + tid * 4);
      }
  }
  const float* b0 = bias;
  const float* b1 = bias + 1536;
  u16* Ct = (u16*)sm;                       // 64 rows x 72 u16 (9KB)
#pragma unroll
  for (int ci = 0; ci < 2; ++ci) {
    const int hcl = wx * 32 + ci * 16 + lc;     // 0..63
    const int hg = hb * 64 + hcl;               // 0..511
    const float bz = b0[hg] + b1[hg];
    const float br = b0[512 + hg] + b1[512 + hg];
    const float b0h = b0[1024 + hg];
    const float b1h = b1[1024 + hg];
    const int ktg = hg >> 5;
    const int gg = (hg >> 3) & 3;
    const size_t hbase = (((size_t)nb * 16 + ktg) * 4 + gg) * 64;
#pragma unroll
    for (int mi = 0; mi < 2; ++mi) {
#pragma unroll
      for (int reg = 0; reg < 4; ++reg) {
        const int nl = wy * 32 + mi * 16 + q * 4 + reg;   // 0..63
        const int n = nb * 64 + nl;
        // t=0: acZ/acR/acT hold x@W; no h part.  t>=1: xp* hold x@W,
        // acZ/acR/acT hold h@U.
        float vZ = acZ[mi][ci][reg] + (first ? 0.0f : xpZ[mi][ci][reg]);
        float vR = acR[mi][ci][reg] + (first ? 0.0f : xpR[mi][ci][reg]);
        float vX = first ? acT[mi][ci][reg] : xpX[mi][ci][reg];
        float vH = first ? 0.0f : acT[mi][ci][reg];
        float z = sigmoidf_(vZ + bz);
        float r = sigmoidf_(vR + br);
        float hh = vX + b0h + r * (vH + b1h);
        hh = fmaxf(hh, 0.0f);
        float hp = 0.0f;
        if (!first) hp = bf16_to_f32(h_in[(hbase + nl) * 8 + (hg & 7)]);
        float v = z * hp + (1.0f - z) * hh;
        if (last) out[(size_t)n * 512 + hg] = v;
        else      Ct[nl * 72 + hcl] = f32_to_bf16(v);
      }
    }
  }
  if (!last) {
    __syncthreads();
    // Re-emit h in granule layout: 512 granules (row64 x g4 x ktl2), 2/thread.
#pragma unroll
    for (int i = 0; i < 2; ++i) {
      int e = i * 256 + tid;
      int row = e & 63;
      int g = (e >> 6) & 3;
      int ktl = e >> 8;                         // 0..1
      u16x8 vv = *(const u16x8*)(Ct + row * 72 + ktl * 32 + g * 8);
      *(u16x8*)(h_out + ((((size_t)nb * 16 + (hb * 2 + ktl)) * 4 + g) * 64 + row) * 8) = vv;
    }
  }
}

// ---------------------------------------------------------------------------
extern "C" void kernel_launch(void* const* d_in, const int* in_sizes, int n_in,
                              void* d_out, int out_size, void* d_ws, size_t ws_size,
                              hipStream_t stream) {
  const float* x = (const float*)d_in[0];    // (128,512,512)
  const float* W = (const float*)d_in[1];    // (512,1536)
  const float* U = (const float*)d_in[2];    // (512,1536)
  const float* bias = (const float*)d_in[3]; // (2,1536)
  float* out = (float*)d_out;                // (128,16384)

  u16* xb = (u16*)d_ws;                      // 64 MiB
  u16* Bt = xb + (size_t)16 * 64 * 32768;    // 3 MiB
  u16* h0 = Bt + (size_t)1536 * 1024;        // 4 MiB
  u16* h1 = h0 + (size_t)4096 * 512;         // 4 MiB
  float* gxA = (float*)(h1 + (size_t)4096 * 512);   // 24 MiB
  float* gxB = gxA + (size_t)512 * 12288;           // 24 MiB (total ~123 MiB)

  pack_x<<<1024, 256, 0, stream>>>(x, xb);
  pack_Bt<<<768, 256, 0, stream>>>(W, U, Bt);

  for (int t = 0; t < 16; ++t) {
    const u16* hin = (t & 1) ? h1 : h0;      // t=0 never reads h
    u16* hout = (t & 1) ? h0 : h1;
    // launch t's GRU reads gx[t] = buf[t&1]; its XW writes gx[t+1] = buf[(t+1)&1]
    const float* gin = (t & 1) ? gxB : gxA;
    float* gout = (t & 1) ? gxA : gxB;
    step_fused<<<1024, 256, 0, stream>>>(
        xb, Bt, bias, hin, hout, gin, gout, out, t,
        (t == 0) ? 1 : 0, (t == 15) ? 1 : 0);
  }
}